// Round 12
// baseline (166.343 us; speedup 1.0000x reference)
//
#include <hip/hip_runtime.h>
#include <hip/hip_cooperative_groups.h>

// BlockinnerAttention: b=1, h=8, T_q=2048, T=4096, dk=64, BS=64, top-2 blocks/query.
// Round 12: SINGLE cooperative dispatch. Phase 1 = round-11 bucket MFMA (SSPLIT=1:
// 512 WGs, one deterministic scan+staging per bucket, 4 waves at tile-stride 4);
// grid.sync() (one grid-wide fence, ~1.4us partials writeback -- the legal version
// of round 8's per-entry fences); phase 2 = grid-stride combine (2 items/thread).
// __launch_bounds__(256,2) guarantees 2 blocks/CU -> 512 WGs co-resident (LDS 29KB).
// hipLaunchCooperativeKernel return code checked -> fall back to the proven
// round-11 2-dispatch path on any failure (identical math -> identical output).

namespace cg = cooperative_groups;

#define NH      8
#define TQ      2048
#define TKV     4096
#define DK      64
#define BSZ     64
#define NB      (TKV / BSZ)     // 64 blocks per head
#define NQ_TOT  (NH * TQ)       // 16384
#define NENT    (NQ_TOT * 2)    // 32768
#define NBUCKET (NH * NB)       // 512
#define CAP     256             // fixed bucket capacity (Poisson(64); P(>256)~0)

// ws layout (bytes): [0, +8.9MB) partials: 32768 entries x 68 floats (o[64],m,l,pad)
#define WS_NEEDED    ((size_t)NENT * 68 * 4)

typedef __attribute__((ext_vector_type(8))) short bf16x8;
typedef __attribute__((ext_vector_type(4))) float f32x4;

__device__ __forceinline__ short f2bf(float x) {
    union { float f; unsigned u; } c; c.f = x;
    unsigned r = c.u + 0x7fffu + ((c.u >> 16) & 1u);   // RNE
    return (short)(r >> 16);
}

__device__ __forceinline__ bf16x8 pack_bf16x8(float4 a, float4 b) {
    bf16x8 r;
    r[0] = f2bf(a.x); r[1] = f2bf(a.y); r[2] = f2bf(a.z); r[3] = f2bf(a.w);
    r[4] = f2bf(b.x); r[5] = f2bf(b.y); r[6] = f2bf(b.z); r[7] = f2bf(b.w);
    return r;
}

#define KSTR 72   // K_lds row stride (shorts): 144 B, 16B-aligned b128 reads
#define VSTR 78   // V_lds row stride (shorts): scalar frag reads conflict-free

// ---- phase 1 body: one bucket per WG (shared buffers passed in) ----
__device__ __forceinline__ void bucket_phase(
    const float* __restrict__ q,
    const float* __restrict__ k,
    const float* __restrict__ v,
    const int*   __restrict__ top2,
    float*       __restrict__ partials,
    int bucket,
    short* K_lds, short* V_lds, short* P_lds_all,
    int* lds_list, int* wave_tot)
{
    const int wave = threadIdx.x >> 6;
    const int lane = threadIdx.x & 63;
    const int W    = wave;                          // worker wave id 0..3

    const int h    = bucket >> 6;
    const int blk  = bucket & (NB - 1);

    // ---- deterministic list build (single WG per bucket) ----
    const int* th = top2 + h * (TQ * 2);            // entries e = h*4096 + i
    int cnt = 0;
#pragma unroll
    for (int rep = 0; rep < (TQ * 2) / 256; ++rep) {
        if ((th[rep * 256 + threadIdx.x] & (NB - 1)) == blk) ++cnt;
    }
    int pre = cnt;
#pragma unroll
    for (int off = 1; off < 64; off <<= 1) {
        const int nb = __shfl_up(pre, off);
        if (lane >= off) pre += nb;
    }
    if (lane == 63) wave_tot[wave] = pre;
    __syncthreads();
    int wbase = 0;
#pragma unroll
    for (int wv = 0; wv < 4; ++wv) if (wv < wave) wbase += wave_tot[wv];
    int nq = wave_tot[0] + wave_tot[1] + wave_tot[2] + wave_tot[3];
    nq = (nq > CAP) ? CAP : nq;
    {
        int p = wbase + pre - cnt;
#pragma unroll
        for (int rep = 0; rep < (TQ * 2) / 256; ++rep) {
            const int i = rep * 256 + threadIdx.x;
            if ((th[i] & (NB - 1)) == blk) {
                if (p < CAP) lds_list[p] = h * (TQ * 2) + i;
                ++p;
            }
        }
    }
    __syncthreads();

    const int ntiles = (nq + 15) >> 4;
    if (ntiles == 0) return;                        // empty bucket (P~e-64)

    const int n16  = lane & 15;
    const int quad = lane >> 4;

    const float* kb = k + ((size_t)h * TKV + (size_t)blk * BSZ) * DK;
    const float* vb = v + ((size_t)h * TKV + (size_t)blk * BSZ) * DK;

    // ---- stage K/V -> LDS (coalesced) ----
    {
        const int row = threadIdx.x >> 2;           // 0..63
        const int seg = threadIdx.x & 3;            // 0..3
        const float* kp = kb + row * DK + seg * 16;
        const float* vp = vb + row * DK + seg * 16;
        short* kd = &K_lds[row * KSTR + seg * 16];
        short* vd = &V_lds[row * VSTR + seg * 16];
#pragma unroll
        for (int c = 0; c < 4; ++c) {
            const float4 a = *(const float4*)(kp + c * 4);
            kd[c * 4 + 0] = f2bf(a.x); kd[c * 4 + 1] = f2bf(a.y);
            kd[c * 4 + 2] = f2bf(a.z); kd[c * 4 + 3] = f2bf(a.w);
            const float4 b = *(const float4*)(vp + c * 4);
            vd[c * 4 + 0] = f2bf(b.x); vd[c * 4 + 1] = f2bf(b.y);
            vd[c * 4 + 2] = f2bf(b.z); vd[c * 4 + 3] = f2bf(b.w);
        }
    }
    __syncthreads();
    if (W >= ntiles) return;

    // ---- K B-frags from LDS ----
    bf16x8 kf[4][2];
#pragma unroll
    for (int kt = 0; kt < 4; ++kt)
#pragma unroll
        for (int ks = 0; ks < 2; ++ks)
            kf[kt][ks] = *(const bf16x8*)&K_lds[(kt * 16 + n16) * KSTR + ks * 32 + quad * 8];

    // ---- V^T B-frags from LDS ----
    bf16x8 vf[4][2];
#pragma unroll
    for (int dt = 0; dt < 4; ++dt)
#pragma unroll
        for (int ks = 0; ks < 2; ++ks) {
            bf16x8 t;
#pragma unroll
            for (int jj = 0; jj < 8; ++jj)
                t[jj] = V_lds[(ks * 32 + quad * 8 + jj) * VSTR + dt * 16 + n16];
            vf[dt][ks] = t;
        }

    short* pl = P_lds_all + wave * (16 * 72);

    for (int t = W; t < ntiles; t += 4) {
        const int tbase = t * 16;

        const int em_idx = (tbase + n16 < nq) ? (tbase + n16) : 0;
        const int qi = lds_list[em_idx] >> 1;
        bf16x8 qf[2];
#pragma unroll
        for (int ks = 0; ks < 2; ++ks) {
            const float* p = q + (size_t)qi * DK + ks * 32 + quad * 8;
            float4 lo = *(const float4*)p, hi = *(const float4*)(p + 4);
            lo.x *= 0.125f; lo.y *= 0.125f; lo.z *= 0.125f; lo.w *= 0.125f;
            hi.x *= 0.125f; hi.y *= 0.125f; hi.z *= 0.125f; hi.w *= 0.125f;
            qf[ks] = pack_bf16x8(lo, hi);
        }

        f32x4 acc[4];
#pragma unroll
        for (int kt = 0; kt < 4; ++kt) {
            f32x4 a = {0.f, 0.f, 0.f, 0.f};
            a = __builtin_amdgcn_mfma_f32_16x16x32_bf16(qf[0], kf[kt][0], a, 0, 0, 0);
            a = __builtin_amdgcn_mfma_f32_16x16x32_bf16(qf[1], kf[kt][1], a, 0, 0, 0);
            acc[kt] = a;
        }

        float m4[4], l4[4], P[4][4];
#pragma unroll
        for (int r = 0; r < 4; ++r) {
            float mx = fmaxf(fmaxf(acc[0][r], acc[1][r]), fmaxf(acc[2][r], acc[3][r]));
            mx = fmaxf(mx, __shfl_xor(mx, 1));
            mx = fmaxf(mx, __shfl_xor(mx, 2));
            mx = fmaxf(mx, __shfl_xor(mx, 4));
            mx = fmaxf(mx, __shfl_xor(mx, 8));
            float s = 0.f;
#pragma unroll
            for (int kt = 0; kt < 4; ++kt) { P[kt][r] = __expf(acc[kt][r] - mx); s += P[kt][r]; }
            s += __shfl_xor(s, 1);
            s += __shfl_xor(s, 2);
            s += __shfl_xor(s, 4);
            s += __shfl_xor(s, 8);
            m4[r] = mx; l4[r] = s;
        }

#pragma unroll
        for (int r = 0; r < 4; ++r)
#pragma unroll
            for (int kt = 0; kt < 4; ++kt)
                pl[(quad * 4 + r) * 72 + kt * 16 + n16] = f2bf(P[kt][r]);

        bf16x8 pf[2];
#pragma unroll
        for (int ks = 0; ks < 2; ++ks)
            pf[ks] = *(const bf16x8*)&pl[n16 * 72 + ks * 32 + quad * 8];

        f32x4 oacc[4];
#pragma unroll
        for (int dt = 0; dt < 4; ++dt) {
            f32x4 a = {0.f, 0.f, 0.f, 0.f};
            a = __builtin_amdgcn_mfma_f32_16x16x32_bf16(pf[0], vf[dt][0], a, 0, 0, 0);
            a = __builtin_amdgcn_mfma_f32_16x16x32_bf16(pf[1], vf[dt][1], a, 0, 0, 0);
            oacc[dt] = a;
        }

#pragma unroll
        for (int r = 0; r < 4; ++r) {
            const int row = tbase + quad * 4 + r;
            if (row < nq) {
                const int e = lds_list[row];
                float* pp = partials + (size_t)e * 68;
#pragma unroll
                for (int dt = 0; dt < 4; ++dt)
                    pp[dt * 16 + n16] = oacc[dt][r];
                if (n16 == 0) pp[64] = m4[r];
                if (n16 == 1) pp[65] = l4[r];
            }
        }
    }
}

__device__ __forceinline__ void combine_item(
    int t, const float* __restrict__ partials, float* __restrict__ out)
{
    const int qi = t >> 4;
    const int dc = t & 15;
    const float* p0 = partials + (size_t)(qi * 2) * 68;
    const float* p1 = p0 + 68;
    const float m0 = p0[64], l0 = p0[65];
    const float m1 = p1[64], l1 = p1[65];
    const float m  = fmaxf(m0, m1);
    const float a0 = __expf(m0 - m), a1 = __expf(m1 - m);
    const float inv = 1.0f / (a0 * l0 + a1 * l1);
    const float4 o0 = *(const float4*)(p0 + dc * 4);
    const float4 o1 = *(const float4*)(p1 + dc * 4);
    float4 o;
    o.x = (o0.x * a0 + o1.x * a1) * inv;
    o.y = (o0.y * a0 + o1.y * a1) * inv;
    o.z = (o0.z * a0 + o1.z * a1) * inv;
    o.w = (o0.w * a0 + o1.w * a1) * inv;
    *(float4*)(out + (size_t)qi * DK + dc * 4) = o;
}

// ---- single cooperative dispatch: phase1 -> grid.sync -> phase2 ----
__global__ __launch_bounds__(256, 2) void fused_kernel(
    const float* __restrict__ q,
    const float* __restrict__ k,
    const float* __restrict__ v,
    const int*   __restrict__ top2,
    float*       __restrict__ partials,
    float*       __restrict__ out)
{
    __shared__ __align__(16) short K_lds[BSZ * KSTR];
    __shared__ __align__(16) short V_lds[BSZ * VSTR];
    __shared__ __align__(16) short P_lds[4 * 16 * 72];
    __shared__ int lds_list[CAP];
    __shared__ int wave_tot[4];

    bucket_phase(q, k, v, top2, partials, blockIdx.x,
                 K_lds, V_lds, P_lds, lds_list, wave_tot);

    cg::this_grid().sync();

    const int nth = gridDim.x * 256;
    for (int t = blockIdx.x * 256 + threadIdx.x; t < NQ_TOT * 16; t += nth)
        combine_item(t, partials, out);
}

// ---- fallback pair (round-11 proven path, same math) ----
__global__ __launch_bounds__(256, 2) void bucket_kernel(
    const float* __restrict__ q,
    const float* __restrict__ k,
    const float* __restrict__ v,
    const int*   __restrict__ top2,
    float*       __restrict__ partials)
{
    __shared__ __align__(16) short K_lds[BSZ * KSTR];
    __shared__ __align__(16) short V_lds[BSZ * VSTR];
    __shared__ __align__(16) short P_lds[4 * 16 * 72];
    __shared__ int lds_list[CAP];
    __shared__ int wave_tot[4];

    bucket_phase(q, k, v, top2, partials, blockIdx.x,
                 K_lds, V_lds, P_lds, lds_list, wave_tot);
}

__global__ __launch_bounds__(256) void combine_kernel(
    const float* __restrict__ partials, float* __restrict__ out)
{
    combine_item(blockIdx.x * 256 + threadIdx.x, partials, out);
}

// ---------------- fallback (round-2 kernel, ws-free) ----------------
__global__ __launch_bounds__(256) void blockattn_fallback(
    const float* __restrict__ q, const float* __restrict__ k,
    const float* __restrict__ v, const int* __restrict__ top2,
    float* __restrict__ out)
{
    const int wave = threadIdx.x >> 6;
    const int lane = threadIdx.x & 63;
    const int qidx = (blockIdx.x << 2) + wave;
    const int bh   = qidx >> 11;
    const int g    = lane >> 4;
    const int dc   = lane & 15;

    const int2 idx = *(const int2*)(top2 + (size_t)qidx * 2);
    const size_t bh_off = (size_t)bh * (TKV * DK);
    const int off = g * DK + dc * 4;

    const float* kb0 = k + bh_off + (size_t)idx.x * (BSZ * DK) + off;
    const float* kb1 = k + bh_off + (size_t)idx.y * (BSZ * DK) + off;
    const float* vb0 = v + bh_off + (size_t)idx.x * (BSZ * DK) + off;
    const float* vb1 = v + bh_off + (size_t)idx.y * (BSZ * DK) + off;
    const float4 qf = *(const float4*)(q + (size_t)qidx * DK + dc * 4);

    float sc[32];
#pragma unroll
    for (int i = 0; i < 16; ++i) {
        const float4 a = *(const float4*)(kb0 + i * 256);
        float p = a.x*qf.x + a.y*qf.y + a.z*qf.z + a.w*qf.w;
        p += __shfl_xor(p,1); p += __shfl_xor(p,2); p += __shfl_xor(p,4); p += __shfl_xor(p,8);
        sc[i] = p * 0.125f;
    }
#pragma unroll
    for (int i = 0; i < 16; ++i) {
        const float4 a = *(const float4*)(kb1 + i * 256);
        float p = a.x*qf.x + a.y*qf.y + a.z*qf.z + a.w*qf.w;
        p += __shfl_xor(p,1); p += __shfl_xor(p,2); p += __shfl_xor(p,4); p += __shfl_xor(p,8);
        sc[16+i] = p * 0.125f;
    }
    float m = sc[0];
#pragma unroll
    for (int i = 1; i < 32; ++i) m = fmaxf(m, sc[i]);
    m = fmaxf(m, __shfl_xor(m,16)); m = fmaxf(m, __shfl_xor(m,32));
    float sum = 0.f;
#pragma unroll
    for (int i = 0; i < 32; ++i) { sc[i] = __expf(sc[i]-m); sum += sc[i]; }
    sum += __shfl_xor(sum,16); sum += __shfl_xor(sum,32);
    const float inv = 1.0f / sum;

    float4 acc = make_float4(0.f,0.f,0.f,0.f);
#pragma unroll
    for (int i = 0; i < 16; ++i) {
        const float4 a = *(const float4*)(vb0 + i * 256);
        acc.x += a.x*sc[i]; acc.y += a.y*sc[i]; acc.z += a.z*sc[i]; acc.w += a.w*sc[i];
    }
#pragma unroll
    for (int i = 0; i < 16; ++i) {
        const float4 a = *(const float4*)(vb1 + i * 256);
        acc.x += a.x*sc[16+i]; acc.y += a.y*sc[16+i]; acc.z += a.z*sc[16+i]; acc.w += a.w*sc[16+i];
    }
    acc.x += __shfl_xor(acc.x,16); acc.y += __shfl_xor(acc.y,16);
    acc.z += __shfl_xor(acc.z,16); acc.w += __shfl_xor(acc.w,16);
    acc.x += __shfl_xor(acc.x,32); acc.y += __shfl_xor(acc.y,32);
    acc.z += __shfl_xor(acc.z,32); acc.w += __shfl_xor(acc.w,32);

    if (g == 0) {
        float4 o;
        o.x = acc.x*inv; o.y = acc.y*inv; o.z = acc.z*inv; o.w = acc.w*inv;
        *(float4*)(out + (size_t)qidx * DK + dc * 4) = o;
    }
}

extern "C" void kernel_launch(void* const* d_in, const int* in_sizes, int n_in,
                              void* d_out, int out_size, void* d_ws, size_t ws_size,
                              hipStream_t stream) {
    const float* q    = (const float*)d_in[0];
    const float* k    = (const float*)d_in[1];
    const float* v    = (const float*)d_in[2];
    // d_in[3] is the scalar BS (=64), baked into kernel constants.
    const int*   top2 = (const int*)d_in[4];
    float*       out  = (float*)d_out;

    if (ws_size < WS_NEEDED) {
        dim3 grid(NQ_TOT / 4), block(256);
        hipLaunchKernelGGL(blockattn_fallback, grid, block, 0, stream, q, k, v, top2, out);
        return;
    }

    float* parts = (float*)d_ws;

    void* args[] = { (void*)&q, (void*)&k, (void*)&v, (void*)&top2,
                     (void*)&parts, (void*)&out };
    hipError_t err = hipLaunchCooperativeKernel(
        (const void*)fused_kernel, dim3(NBUCKET), dim3(256), args, 0, stream);

    if (err != hipSuccess) {
        // proven round-11-style 2-dispatch path (identical math -> identical output)
        hipLaunchKernelGGL(bucket_kernel,  dim3(NBUCKET), dim3(256), 0, stream,
                           q, k, v, top2, parts);
        hipLaunchKernelGGL(combine_kernel, dim3(NQ_TOT * 16 / 256), dim3(256), 0, stream,
                           parts, out);
    }
}

// Round 13
// 85.056 us; speedup vs baseline: 1.9557x; 1.9557x over previous
//
#include <hip/hip_runtime.h>

// BlockinnerAttention: b=1, h=8, T_q=2048, T=4096, dk=64, BS=64, top-2 blocks/query.
// Round 13: round-11 structure restored (best: 83.5us). Round-12's cooperative
// grid.sync cost ~70us -- cross-XCD coherence (L2 wb/inv + spin) is catastrophic
// on gfx950; the kernel boundary is the only cheap grid-wide fence, so 2
// dispatches is the structural minimum for split-K. New here: bf16 partials
// (272 -> 144 B/entry: 64 bf16 o + fp32 m,l) halving partial write+read traffic.
// Pipeline: bucket (MFMA, deterministic LDS list build) -> combine.

#define NH      8
#define TQ      2048
#define TKV     4096
#define DK      64
#define BSZ     64
#define NB      (TKV / BSZ)     // 64 blocks per head
#define NQ_TOT  (NH * TQ)       // 16384
#define NENT    (NQ_TOT * 2)    // 32768
#define NBUCKET (NH * NB)       // 512
#define SSPLIT  2               // sub-WGs per bucket -> 8 worker waves/bucket
#define CAP     256             // fixed bucket capacity (Poisson(64); P(>256)~0)

// ws: partials, 144 B/entry = 72 shorts: [0:64)=o bf16, float m @short 64, float l @short 66
#define PSTR    72              // shorts per partial entry (144 B, 16B-aligned)
#define WS_NEEDED ((size_t)NENT * PSTR * 2)

typedef __attribute__((ext_vector_type(8))) short bf16x8;
typedef __attribute__((ext_vector_type(4))) float f32x4;

__device__ __forceinline__ short f2bf(float x) {
    union { float f; unsigned u; } c; c.f = x;
    unsigned r = c.u + 0x7fffu + ((c.u >> 16) & 1u);   // RNE
    return (short)(r >> 16);
}

__device__ __forceinline__ float bf2f(short s) {
    union { unsigned u; float f; } c; c.u = ((unsigned)(unsigned short)s) << 16;
    return c.f;
}

__device__ __forceinline__ bf16x8 pack_bf16x8(float4 a, float4 b) {
    bf16x8 r;
    r[0] = f2bf(a.x); r[1] = f2bf(a.y); r[2] = f2bf(a.z); r[3] = f2bf(a.w);
    r[4] = f2bf(b.x); r[5] = f2bf(b.y); r[6] = f2bf(b.z); r[7] = f2bf(b.w);
    return r;
}

#define KSTR 72   // K_lds row stride (shorts): 144 B, 16B-aligned b128 reads
#define VSTR 78   // V_lds row stride (shorts): scalar frag reads conflict-free

__global__ __launch_bounds__(256, 2) void bucket_kernel(
    const float* __restrict__ q,
    const float* __restrict__ k,
    const float* __restrict__ v,
    const int*   __restrict__ top2,
    short*       __restrict__ partials)
{
    __shared__ __align__(16) short K_lds[BSZ * KSTR];   // K[row][col] bf16
    __shared__ __align__(16) short V_lds[BSZ * VSTR];   // V[row][col] bf16
    __shared__ __align__(16) short P_lds[4][16 * 72];   // per-wave P buffer
    __shared__ int lds_list[CAP];
    __shared__ int wave_tot[4];

    const int bucket  = blockIdx.x & (NBUCKET - 1);
    const int subtile = blockIdx.x >> 9;            // 0..SSPLIT-1
    const int wave = threadIdx.x >> 6;
    const int lane = threadIdx.x & 63;
    const int W    = subtile * 4 + wave;            // worker wave id 0..7

    const int h    = bucket >> 6;
    const int blk  = bucket & (NB - 1);

    // ---- deterministic list build: identical in both sub-WGs ----
    const int* th = top2 + h * (TQ * 2);            // entries e = h*4096 + i
    int cnt = 0;
#pragma unroll
    for (int rep = 0; rep < (TQ * 2) / 256; ++rep) {
        if ((th[rep * 256 + threadIdx.x] & (NB - 1)) == blk) ++cnt;
    }
    int pre = cnt;
#pragma unroll
    for (int off = 1; off < 64; off <<= 1) {
        const int nb = __shfl_up(pre, off);
        if (lane >= off) pre += nb;
    }
    if (lane == 63) wave_tot[wave] = pre;
    __syncthreads();
    int wbase = 0;
#pragma unroll
    for (int wv = 0; wv < 4; ++wv) if (wv < wave) wbase += wave_tot[wv];
    int nq = wave_tot[0] + wave_tot[1] + wave_tot[2] + wave_tot[3];
    nq = (nq > CAP) ? CAP : nq;
    {
        int p = wbase + pre - cnt;
#pragma unroll
        for (int rep = 0; rep < (TQ * 2) / 256; ++rep) {
            const int i = rep * 256 + threadIdx.x;
            if ((th[i] & (NB - 1)) == blk) {
                if (p < CAP) lds_list[p] = h * (TQ * 2) + i;
                ++p;
            }
        }
    }
    __syncthreads();

    const int ntiles = (nq + 15) >> 4;
    if (ntiles <= subtile * 4) return;              // whole WG idle (uniform)

    const int n16  = lane & 15;
    const int quad = lane >> 4;

    const float* kb = k + ((size_t)h * TKV + (size_t)blk * BSZ) * DK;
    const float* vb = v + ((size_t)h * TKV + (size_t)blk * BSZ) * DK;

    // ---- stage K/V -> LDS (coalesced) ----
    {
        const int row = threadIdx.x >> 2;           // 0..63
        const int seg = threadIdx.x & 3;            // 0..3
        const float* kp = kb + row * DK + seg * 16;
        const float* vp = vb + row * DK + seg * 16;
        short* kd = &K_lds[row * KSTR + seg * 16];
        short* vd = &V_lds[row * VSTR + seg * 16];
#pragma unroll
        for (int c = 0; c < 4; ++c) {
            const float4 a = *(const float4*)(kp + c * 4);
            kd[c * 4 + 0] = f2bf(a.x); kd[c * 4 + 1] = f2bf(a.y);
            kd[c * 4 + 2] = f2bf(a.z); kd[c * 4 + 3] = f2bf(a.w);
            const float4 b = *(const float4*)(vp + c * 4);
            vd[c * 4 + 0] = f2bf(b.x); vd[c * 4 + 1] = f2bf(b.y);
            vd[c * 4 + 2] = f2bf(b.z); vd[c * 4 + 3] = f2bf(b.w);
        }
    }
    __syncthreads();
    if (W >= ntiles) return;                        // idle waves exit after sync

    // ---- K B-frags from LDS ----
    bf16x8 kf[4][2];
#pragma unroll
    for (int kt = 0; kt < 4; ++kt)
#pragma unroll
        for (int ks = 0; ks < 2; ++ks)
            kf[kt][ks] = *(const bf16x8*)&K_lds[(kt * 16 + n16) * KSTR + ks * 32 + quad * 8];

    // ---- V^T B-frags from LDS ----
    bf16x8 vf[4][2];
#pragma unroll
    for (int dt = 0; dt < 4; ++dt)
#pragma unroll
        for (int ks = 0; ks < 2; ++ks) {
            bf16x8 t;
#pragma unroll
            for (int jj = 0; jj < 8; ++jj)
                t[jj] = V_lds[(ks * 32 + quad * 8 + jj) * VSTR + dt * 16 + n16];
            vf[dt][ks] = t;
        }

    short* pl = &P_lds[wave][0];

    for (int t = W; t < ntiles; t += 4 * SSPLIT) {
        const int tbase = t * 16;

        const int em_idx = (tbase + n16 < nq) ? (tbase + n16) : 0;
        const int qi = lds_list[em_idx] >> 1;
        bf16x8 qf[2];
#pragma unroll
        for (int ks = 0; ks < 2; ++ks) {
            const float* p = q + (size_t)qi * DK + ks * 32 + quad * 8;
            float4 lo = *(const float4*)p, hi = *(const float4*)(p + 4);
            lo.x *= 0.125f; lo.y *= 0.125f; lo.z *= 0.125f; lo.w *= 0.125f;
            hi.x *= 0.125f; hi.y *= 0.125f; hi.z *= 0.125f; hi.w *= 0.125f;
            qf[ks] = pack_bf16x8(lo, hi);
        }

        f32x4 acc[4];
#pragma unroll
        for (int kt = 0; kt < 4; ++kt) {
            f32x4 a = {0.f, 0.f, 0.f, 0.f};
            a = __builtin_amdgcn_mfma_f32_16x16x32_bf16(qf[0], kf[kt][0], a, 0, 0, 0);
            a = __builtin_amdgcn_mfma_f32_16x16x32_bf16(qf[1], kf[kt][1], a, 0, 0, 0);
            acc[kt] = a;
        }

        float m4[4], l4[4], P[4][4];
#pragma unroll
        for (int r = 0; r < 4; ++r) {
            float mx = fmaxf(fmaxf(acc[0][r], acc[1][r]), fmaxf(acc[2][r], acc[3][r]));
            mx = fmaxf(mx, __shfl_xor(mx, 1));
            mx = fmaxf(mx, __shfl_xor(mx, 2));
            mx = fmaxf(mx, __shfl_xor(mx, 4));
            mx = fmaxf(mx, __shfl_xor(mx, 8));
            float s = 0.f;
#pragma unroll
            for (int kt = 0; kt < 4; ++kt) { P[kt][r] = __expf(acc[kt][r] - mx); s += P[kt][r]; }
            s += __shfl_xor(s, 1);
            s += __shfl_xor(s, 2);
            s += __shfl_xor(s, 4);
            s += __shfl_xor(s, 8);
            m4[r] = mx; l4[r] = s;
        }

#pragma unroll
        for (int r = 0; r < 4; ++r)
#pragma unroll
            for (int kt = 0; kt < 4; ++kt)
                pl[(quad * 4 + r) * 72 + kt * 16 + n16] = f2bf(P[kt][r]);

        bf16x8 pf[2];
#pragma unroll
        for (int ks = 0; ks < 2; ++ks)
            pf[ks] = *(const bf16x8*)&pl[n16 * 72 + ks * 32 + quad * 8];

        f32x4 oacc[4];
#pragma unroll
        for (int dt = 0; dt < 4; ++dt) {
            f32x4 a = {0.f, 0.f, 0.f, 0.f};
            a = __builtin_amdgcn_mfma_f32_16x16x32_bf16(pf[0], vf[dt][0], a, 0, 0, 0);
            a = __builtin_amdgcn_mfma_f32_16x16x32_bf16(pf[1], vf[dt][1], a, 0, 0, 0);
            oacc[dt] = a;
        }

        // ---- store bf16 partials (o bf16[64], m fp32 @short64, l fp32 @short66)
#pragma unroll
        for (int r = 0; r < 4; ++r) {
            const int row = tbase + quad * 4 + r;
            if (row < nq) {
                const int e = lds_list[row];
                short* pp = partials + (size_t)e * PSTR;
#pragma unroll
                for (int dt = 0; dt < 4; ++dt)
                    pp[dt * 16 + n16] = f2bf(oacc[dt][r]);
                if (n16 == 0) *(float*)(pp + 64) = m4[r];
                if (n16 == 1) *(float*)(pp + 66) = l4[r];
            }
        }
    }
}

__global__ __launch_bounds__(256) void combine_kernel(
    const short* __restrict__ partials, float* __restrict__ out)
{
    const int t  = blockIdx.x * 256 + threadIdx.x;  // NQ_TOT*8 threads
    const int qi = t >> 3;
    const int dc = t & 7;                           // 8 dims per thread
    const short* p0 = partials + (size_t)(qi * 2) * PSTR;
    const short* p1 = p0 + PSTR;
    const float m0 = *(const float*)(p0 + 64), l0 = *(const float*)(p0 + 66);
    const float m1 = *(const float*)(p1 + 64), l1 = *(const float*)(p1 + 66);
    const float m  = fmaxf(m0, m1);
    const float a0 = __expf(m0 - m), a1 = __expf(m1 - m);
    const float inv = 1.0f / (a0 * l0 + a1 * l1);
    const bf16x8 o0 = *(const bf16x8*)(p0 + dc * 8);    // 16B-aligned
    const bf16x8 o1 = *(const bf16x8*)(p1 + dc * 8);
    float4 lo, hi;
    lo.x = (bf2f(o0[0]) * a0 + bf2f(o1[0]) * a1) * inv;
    lo.y = (bf2f(o0[1]) * a0 + bf2f(o1[1]) * a1) * inv;
    lo.z = (bf2f(o0[2]) * a0 + bf2f(o1[2]) * a1) * inv;
    lo.w = (bf2f(o0[3]) * a0 + bf2f(o1[3]) * a1) * inv;
    hi.x = (bf2f(o0[4]) * a0 + bf2f(o1[4]) * a1) * inv;
    hi.y = (bf2f(o0[5]) * a0 + bf2f(o1[5]) * a1) * inv;
    hi.z = (bf2f(o0[6]) * a0 + bf2f(o1[6]) * a1) * inv;
    hi.w = (bf2f(o0[7]) * a0 + bf2f(o1[7]) * a1) * inv;
    float* op = out + (size_t)qi * DK + dc * 8;
    *(float4*)op = lo;
    *(float4*)(op + 4) = hi;
}

// ---------------- fallback (round-2 kernel, ws-free) ----------------
__global__ __launch_bounds__(256) void blockattn_fallback(
    const float* __restrict__ q, const float* __restrict__ k,
    const float* __restrict__ v, const int* __restrict__ top2,
    float* __restrict__ out)
{
    const int wave = threadIdx.x >> 6;
    const int lane = threadIdx.x & 63;
    const int qidx = (blockIdx.x << 2) + wave;
    const int bh   = qidx >> 11;
    const int g    = lane >> 4;
    const int dc   = lane & 15;

    const int2 idx = *(const int2*)(top2 + (size_t)qidx * 2);
    const size_t bh_off = (size_t)bh * (TKV * DK);
    const int off = g * DK + dc * 4;

    const float* kb0 = k + bh_off + (size_t)idx.x * (BSZ * DK) + off;
    const float* kb1 = k + bh_off + (size_t)idx.y * (BSZ * DK) + off;
    const float* vb0 = v + bh_off + (size_t)idx.x * (BSZ * DK) + off;
    const float* vb1 = v + bh_off + (size_t)idx.y * (BSZ * DK) + off;
    const float4 qf = *(const float4*)(q + (size_t)qidx * DK + dc * 4);

    float sc[32];
#pragma unroll
    for (int i = 0; i < 16; ++i) {
        const float4 a = *(const float4*)(kb0 + i * 256);
        float p = a.x*qf.x + a.y*qf.y + a.z*qf.z + a.w*qf.w;
        p += __shfl_xor(p,1); p += __shfl_xor(p,2); p += __shfl_xor(p,4); p += __shfl_xor(p,8);
        sc[i] = p * 0.125f;
    }
#pragma unroll
    for (int i = 0; i < 16; ++i) {
        const float4 a = *(const float4*)(kb1 + i * 256);
        float p = a.x*qf.x + a.y*qf.y + a.z*qf.z + a.w*qf.w;
        p += __shfl_xor(p,1); p += __shfl_xor(p,2); p += __shfl_xor(p,4); p += __shfl_xor(p,8);
        sc[16+i] = p * 0.125f;
    }
    float m = sc[0];
#pragma unroll
    for (int i = 1; i < 32; ++i) m = fmaxf(m, sc[i]);
    m = fmaxf(m, __shfl_xor(m,16)); m = fmaxf(m, __shfl_xor(m,32));
    float sum = 0.f;
#pragma unroll
    for (int i = 0; i < 32; ++i) { sc[i] = __expf(sc[i]-m); sum += sc[i]; }
    sum += __shfl_xor(sum,16); sum += __shfl_xor(sum,32);
    const float inv = 1.0f / sum;

    float4 acc = make_float4(0.f,0.f,0.f,0.f);
#pragma unroll
    for (int i = 0; i < 16; ++i) {
        const float4 a = *(const float4*)(vb0 + i * 256);
        acc.x += a.x*sc[i]; acc.y += a.y*sc[i]; acc.z += a.z*sc[i]; acc.w += a.w*sc[i];
    }
#pragma unroll
    for (int i = 0; i < 16; ++i) {
        const float4 a = *(const float4*)(vb1 + i * 256);
        acc.x += a.x*sc[16+i]; acc.y += a.y*sc[16+i]; acc.z += a.z*sc[16+i]; acc.w += a.w*sc[16+i];
    }
    acc.x += __shfl_xor(acc.x,16); acc.y += __shfl_xor(acc.y,16);
    acc.z += __shfl_xor(acc.z,16); acc.w += __shfl_xor(acc.w,16);
    acc.x += __shfl_xor(acc.x,32); acc.y += __shfl_xor(acc.y,32);
    acc.z += __shfl_xor(acc.z,32); acc.w += __shfl_xor(acc.w,32);

    if (g == 0) {
        float4 o;
        o.x = acc.x*inv; o.y = acc.y*inv; o.z = acc.z*inv; o.w = acc.w*inv;
        *(float4*)(out + (size_t)qidx * DK + dc * 4) = o;
    }
}

extern "C" void kernel_launch(void* const* d_in, const int* in_sizes, int n_in,
                              void* d_out, int out_size, void* d_ws, size_t ws_size,
                              hipStream_t stream) {
    const float* q    = (const float*)d_in[0];
    const float* k    = (const float*)d_in[1];
    const float* v    = (const float*)d_in[2];
    // d_in[3] is the scalar BS (=64), baked into kernel constants.
    const int*   top2 = (const int*)d_in[4];
    float*       out  = (float*)d_out;

    if (ws_size < WS_NEEDED) {
        dim3 grid(NQ_TOT / 4), block(256);
        hipLaunchKernelGGL(blockattn_fallback, grid, block, 0, stream, q, k, v, top2, out);
        return;
    }

    short* parts = (short*)d_ws;

    hipLaunchKernelGGL(bucket_kernel,  dim3(NBUCKET * SSPLIT), dim3(256), 0, stream,
                       q, k, v, top2, parts);
    hipLaunchKernelGGL(combine_kernel, dim3(NQ_TOT * 8 / 256), dim3(256), 0, stream,
                       parts, out);
}

// Round 14
// 83.304 us; speedup vs baseline: 1.9968x; 1.0210x over previous
//
#include <hip/hip_runtime.h>

// BlockinnerAttention: b=1, h=8, T_q=2048, T=4096, dk=64, BS=64, top-2 blocks/query.
// FINAL (= round 11, best measured: 83.5us): 2-dispatch split-K flash-bucket.
//   bucket_kernel: one (head,block) bucket per WG-pair (SSPLIT=2); deterministic
//     LDS list build (count -> shfl_up prefix scan -> ordered write, identical
//     in both sub-WGs); K/V staged once per WG into LDS (coalesced float4 ->
//     bf16); per 16-query tile: S=(Q/8)K^T via mfma_16x16x32_bf16, register
//     softmax (m,l), P through per-wave LDS slice, O=P V^T; fp32 partials.
//   combine_kernel: exact flash merge of the 2 partials per query.
// Structure notes (measured): 2 dispatches is the minimum -- in-kernel fences
// (r8) and cooperative grid.sync (r12) both catastrophically slow on gfx950's
// non-coherent per-XCD L2s; bf16 partials (r13) neutral-to-worse; kernels are
// dispatch/fixed-overhead-bound, not HW-pipe-bound.

#define NH      8
#define TQ      2048
#define TKV     4096
#define DK      64
#define BSZ     64
#define NB      (TKV / BSZ)     // 64 blocks per head
#define NQ_TOT  (NH * TQ)       // 16384
#define NENT    (NQ_TOT * 2)    // 32768
#define NBUCKET (NH * NB)       // 512
#define SSPLIT  2               // sub-WGs per bucket -> 8 worker waves/bucket
#define CAP     256             // fixed bucket capacity (Poisson(64); P(>256)~0)

// ws layout (bytes): [0, +8.9MB) partials: 32768 entries x 68 floats (o[64],m,l,pad)
#define WS_NEEDED    ((size_t)NENT * 68 * 4)

typedef __attribute__((ext_vector_type(8))) short bf16x8;
typedef __attribute__((ext_vector_type(4))) float f32x4;

__device__ __forceinline__ short f2bf(float x) {
    union { float f; unsigned u; } c; c.f = x;
    unsigned r = c.u + 0x7fffu + ((c.u >> 16) & 1u);   // RNE
    return (short)(r >> 16);
}

__device__ __forceinline__ bf16x8 pack_bf16x8(float4 a, float4 b) {
    bf16x8 r;
    r[0] = f2bf(a.x); r[1] = f2bf(a.y); r[2] = f2bf(a.z); r[3] = f2bf(a.w);
    r[4] = f2bf(b.x); r[5] = f2bf(b.y); r[6] = f2bf(b.z); r[7] = f2bf(b.w);
    return r;
}

#define KSTR 72   // K_lds row stride (shorts): 144 B, 16B-aligned b128 reads
#define VSTR 78   // V_lds row stride (shorts): scalar frag reads conflict-free

__global__ __launch_bounds__(256, 2) void bucket_kernel(
    const float* __restrict__ q,
    const float* __restrict__ k,
    const float* __restrict__ v,
    const int*   __restrict__ top2,
    float*       __restrict__ partials)
{
    __shared__ __align__(16) short K_lds[BSZ * KSTR];   // K[row][col] bf16
    __shared__ __align__(16) short V_lds[BSZ * VSTR];   // V[row][col] bf16
    __shared__ __align__(16) short P_lds[4][16 * 72];   // per-wave P buffer
    __shared__ int lds_list[CAP];
    __shared__ int wave_tot[4];

    const int bucket  = blockIdx.x & (NBUCKET - 1);
    const int subtile = blockIdx.x >> 9;            // 0..SSPLIT-1
    const int wave = threadIdx.x >> 6;
    const int lane = threadIdx.x & 63;
    const int W    = subtile * 4 + wave;            // worker wave id 0..7

    const int h    = bucket >> 6;
    const int blk  = bucket & (NB - 1);

    // ---- deterministic list build: identical in both sub-WGs ----
    const int* th = top2 + h * (TQ * 2);            // entries e = h*4096 + i
    int cnt = 0;
#pragma unroll
    for (int rep = 0; rep < (TQ * 2) / 256; ++rep) {
        if ((th[rep * 256 + threadIdx.x] & (NB - 1)) == blk) ++cnt;
    }
    int pre = cnt;
#pragma unroll
    for (int off = 1; off < 64; off <<= 1) {
        const int nb = __shfl_up(pre, off);
        if (lane >= off) pre += nb;
    }
    if (lane == 63) wave_tot[wave] = pre;
    __syncthreads();
    int wbase = 0;
#pragma unroll
    for (int wv = 0; wv < 4; ++wv) if (wv < wave) wbase += wave_tot[wv];
    int nq = wave_tot[0] + wave_tot[1] + wave_tot[2] + wave_tot[3];
    nq = (nq > CAP) ? CAP : nq;
    {
        int p = wbase + pre - cnt;
#pragma unroll
        for (int rep = 0; rep < (TQ * 2) / 256; ++rep) {
            const int i = rep * 256 + threadIdx.x;
            if ((th[i] & (NB - 1)) == blk) {
                if (p < CAP) lds_list[p] = h * (TQ * 2) + i;
                ++p;
            }
        }
    }
    __syncthreads();

    const int ntiles = (nq + 15) >> 4;
    if (ntiles <= subtile * 4) return;              // whole WG idle (uniform)

    const int n16  = lane & 15;                     // n / m / col index
    const int quad = lane >> 4;                     // 0..3

    const float* kb = k + ((size_t)h * TKV + (size_t)blk * BSZ) * DK;
    const float* vb = v + ((size_t)h * TKV + (size_t)blk * BSZ) * DK;

    // ---- stage K/V -> LDS (coalesced: thread t loads 16 floats of each) ----
    {
        const int row = threadIdx.x >> 2;           // 0..63
        const int seg = threadIdx.x & 3;            // 0..3 (16-float segment)
        const float* kp = kb + row * DK + seg * 16;
        const float* vp = vb + row * DK + seg * 16;
        short* kd = &K_lds[row * KSTR + seg * 16];
        short* vd = &V_lds[row * VSTR + seg * 16];
#pragma unroll
        for (int c = 0; c < 4; ++c) {
            const float4 a = *(const float4*)(kp + c * 4);
            kd[c * 4 + 0] = f2bf(a.x); kd[c * 4 + 1] = f2bf(a.y);
            kd[c * 4 + 2] = f2bf(a.z); kd[c * 4 + 3] = f2bf(a.w);
            const float4 b = *(const float4*)(vp + c * 4);
            vd[c * 4 + 0] = f2bf(b.x); vd[c * 4 + 1] = f2bf(b.y);
            vd[c * 4 + 2] = f2bf(b.z); vd[c * 4 + 3] = f2bf(b.w);
        }
    }
    __syncthreads();
    if (W >= ntiles) return;                        // idle waves exit after sync

    // ---- K B-frags from LDS: kf[kt][ks] = K[kt*16+n16][ks*32+quad*8 .. +7]
    bf16x8 kf[4][2];
#pragma unroll
    for (int kt = 0; kt < 4; ++kt)
#pragma unroll
        for (int ks = 0; ks < 2; ++ks)
            kf[kt][ks] = *(const bf16x8*)&K_lds[(kt * 16 + n16) * KSTR + ks * 32 + quad * 8];

    // ---- V^T B-frags from LDS: vf[dt][ks][jj] = V[ks*32+quad*8+jj][dt*16+n16]
    bf16x8 vf[4][2];
#pragma unroll
    for (int dt = 0; dt < 4; ++dt)
#pragma unroll
        for (int ks = 0; ks < 2; ++ks) {
            bf16x8 t;
#pragma unroll
            for (int jj = 0; jj < 8; ++jj)
                t[jj] = V_lds[(ks * 32 + quad * 8 + jj) * VSTR + dt * 16 + n16];
            vf[dt][ks] = t;
        }

    short* pl = &P_lds[wave][0];

    for (int t = W; t < ntiles; t += 4 * SSPLIT) {
        const int tbase = t * 16;

        // ---- Q A-frag: row m=n16 of this tile (pad rows -> entry 0 of bucket)
        const int em_idx = (tbase + n16 < nq) ? (tbase + n16) : 0;
        const int qi = lds_list[em_idx] >> 1;
        bf16x8 qf[2];
#pragma unroll
        for (int ks = 0; ks < 2; ++ks) {
            const float* p = q + (size_t)qi * DK + ks * 32 + quad * 8;
            float4 lo = *(const float4*)p, hi = *(const float4*)(p + 4);
            lo.x *= 0.125f; lo.y *= 0.125f; lo.z *= 0.125f; lo.w *= 0.125f;
            hi.x *= 0.125f; hi.y *= 0.125f; hi.z *= 0.125f; hi.w *= 0.125f;
            qf[ks] = pack_bf16x8(lo, hi);
        }

        // ---- S = (Q/8) K^T : acc[kt] C-layout row=quad*4+r (q), col=n16 (key)
        f32x4 acc[4];
#pragma unroll
        for (int kt = 0; kt < 4; ++kt) {
            f32x4 a = {0.f, 0.f, 0.f, 0.f};
            a = __builtin_amdgcn_mfma_f32_16x16x32_bf16(qf[0], kf[kt][0], a, 0, 0, 0);
            a = __builtin_amdgcn_mfma_f32_16x16x32_bf16(qf[1], kf[kt][1], a, 0, 0, 0);
            acc[kt] = a;
        }

        // ---- softmax per row-slot r (rows quad*4+r): reduce over kt + lane&15
        float m4[4], l4[4], P[4][4];
#pragma unroll
        for (int r = 0; r < 4; ++r) {
            float mx = fmaxf(fmaxf(acc[0][r], acc[1][r]), fmaxf(acc[2][r], acc[3][r]));
            mx = fmaxf(mx, __shfl_xor(mx, 1));
            mx = fmaxf(mx, __shfl_xor(mx, 2));
            mx = fmaxf(mx, __shfl_xor(mx, 4));
            mx = fmaxf(mx, __shfl_xor(mx, 8));
            float s = 0.f;
#pragma unroll
            for (int kt = 0; kt < 4; ++kt) { P[kt][r] = __expf(acc[kt][r] - mx); s += P[kt][r]; }
            s += __shfl_xor(s, 1);
            s += __shfl_xor(s, 2);
            s += __shfl_xor(s, 4);
            s += __shfl_xor(s, 8);
            m4[r] = mx; l4[r] = s;
        }

        // ---- P -> LDS (bf16, C-layout write): row=quad*4+r, col=kt*16+n16
#pragma unroll
        for (int r = 0; r < 4; ++r)
#pragma unroll
            for (int kt = 0; kt < 4; ++kt)
                pl[(quad * 4 + r) * 72 + kt * 16 + n16] = f2bf(P[kt][r]);

        // ---- P A-frags: lane m=n16 reads k=ks*32+quad*8..+7 (16B aligned)
        bf16x8 pf[2];
#pragma unroll
        for (int ks = 0; ks < 2; ++ks)
            pf[ks] = *(const bf16x8*)&pl[n16 * 72 + ks * 32 + quad * 8];

        // ---- O = P V^T : oacc[dt] row=quad*4+r (q), col=n16 (dim)
        f32x4 oacc[4];
#pragma unroll
        for (int dt = 0; dt < 4; ++dt) {
            f32x4 a = {0.f, 0.f, 0.f, 0.f};
            a = __builtin_amdgcn_mfma_f32_16x16x32_bf16(pf[0], vf[dt][0], a, 0, 0, 0);
            a = __builtin_amdgcn_mfma_f32_16x16x32_bf16(pf[1], vf[dt][1], a, 0, 0, 0);
            oacc[dt] = a;
        }

        // ---- store partials (unnormalized o, m, l) for real rows
#pragma unroll
        for (int r = 0; r < 4; ++r) {
            const int row = tbase + quad * 4 + r;
            if (row < nq) {
                const int e = lds_list[row];
                float* pp = partials + (size_t)e * 68;
#pragma unroll
                for (int dt = 0; dt < 4; ++dt)
                    pp[dt * 16 + n16] = oacc[dt][r];
                if (n16 == 0) pp[64] = m4[r];
                if (n16 == 1) pp[65] = l4[r];
            }
        }
    }
}

__global__ __launch_bounds__(256) void combine_kernel(
    const float* __restrict__ partials, float* __restrict__ out)
{
    const int t  = blockIdx.x * 256 + threadIdx.x;  // NQ_TOT*16 threads
    const int qi = t >> 4;
    const int dc = t & 15;
    const float* p0 = partials + (size_t)(qi * 2) * 68;
    const float* p1 = p0 + 68;
    const float m0 = p0[64], l0 = p0[65];
    const float m1 = p1[64], l1 = p1[65];
    const float m  = fmaxf(m0, m1);
    const float a0 = __expf(m0 - m), a1 = __expf(m1 - m);
    const float inv = 1.0f / (a0 * l0 + a1 * l1);
    const float4 o0 = *(const float4*)(p0 + dc * 4);
    const float4 o1 = *(const float4*)(p1 + dc * 4);
    float4 o;
    o.x = (o0.x * a0 + o1.x * a1) * inv;
    o.y = (o0.y * a0 + o1.y * a1) * inv;
    o.z = (o0.z * a0 + o1.z * a1) * inv;
    o.w = (o0.w * a0 + o1.w * a1) * inv;
    *(float4*)(out + (size_t)qi * DK + dc * 4) = o;
}

// ---------------- fallback (round-2 kernel, ws-free) ----------------
__global__ __launch_bounds__(256) void blockattn_fallback(
    const float* __restrict__ q, const float* __restrict__ k,
    const float* __restrict__ v, const int* __restrict__ top2,
    float* __restrict__ out)
{
    const int wave = threadIdx.x >> 6;
    const int lane = threadIdx.x & 63;
    const int qidx = (blockIdx.x << 2) + wave;
    const int bh   = qidx >> 11;
    const int g    = lane >> 4;
    const int dc   = lane & 15;

    const int2 idx = *(const int2*)(top2 + (size_t)qidx * 2);
    const size_t bh_off = (size_t)bh * (TKV * DK);
    const int off = g * DK + dc * 4;

    const float* kb0 = k + bh_off + (size_t)idx.x * (BSZ * DK) + off;
    const float* kb1 = k + bh_off + (size_t)idx.y * (BSZ * DK) + off;
    const float* vb0 = v + bh_off + (size_t)idx.x * (BSZ * DK) + off;
    const float* vb1 = v + bh_off + (size_t)idx.y * (BSZ * DK) + off;
    const float4 qf = *(const float4*)(q + (size_t)qidx * DK + dc * 4);

    float sc[32];
#pragma unroll
    for (int i = 0; i < 16; ++i) {
        const float4 a = *(const float4*)(kb0 + i * 256);
        float p = a.x*qf.x + a.y*qf.y + a.z*qf.z + a.w*qf.w;
        p += __shfl_xor(p,1); p += __shfl_xor(p,2); p += __shfl_xor(p,4); p += __shfl_xor(p,8);
        sc[i] = p * 0.125f;
    }
#pragma unroll
    for (int i = 0; i < 16; ++i) {
        const float4 a = *(const float4*)(kb1 + i * 256);
        float p = a.x*qf.x + a.y*qf.y + a.z*qf.z + a.w*qf.w;
        p += __shfl_xor(p,1); p += __shfl_xor(p,2); p += __shfl_xor(p,4); p += __shfl_xor(p,8);
        sc[16+i] = p * 0.125f;
    }
    float m = sc[0];
#pragma unroll
    for (int i = 1; i < 32; ++i) m = fmaxf(m, sc[i]);
    m = fmaxf(m, __shfl_xor(m,16)); m = fmaxf(m, __shfl_xor(m,32));
    float sum = 0.f;
#pragma unroll
    for (int i = 0; i < 32; ++i) { sc[i] = __expf(sc[i]-m); sum += sc[i]; }
    sum += __shfl_xor(sum,16); sum += __shfl_xor(sum,32);
    const float inv = 1.0f / sum;

    float4 acc = make_float4(0.f,0.f,0.f,0.f);
#pragma unroll
    for (int i = 0; i < 16; ++i) {
        const float4 a = *(const float4*)(vb0 + i * 256);
        acc.x += a.x*sc[i]; acc.y += a.y*sc[i]; acc.z += a.z*sc[i]; acc.w += a.w*sc[i];
    }
#pragma unroll
    for (int i = 0; i < 16; ++i) {
        const float4 a = *(const float4*)(vb1 + i * 256);
        acc.x += a.x*sc[16+i]; acc.y += a.y*sc[16+i]; acc.z += a.z*sc[16+i]; acc.w += a.w*sc[16+i];
    }
    acc.x += __shfl_xor(acc.x,16); acc.y += __shfl_xor(acc.y,16);
    acc.z += __shfl_xor(acc.z,16); acc.w += __shfl_xor(acc.w,16);
    acc.x += __shfl_xor(acc.x,32); acc.y += __shfl_xor(acc.y,32);
    acc.z += __shfl_xor(acc.z,32); acc.w += __shfl_xor(acc.w,32);

    if (g == 0) {
        float4 o;
        o.x = acc.x*inv; o.y = acc.y*inv; o.z = acc.z*inv; o.w = acc.w*inv;
        *(float4*)(out + (size_t)qidx * DK + dc * 4) = o;
    }
}

extern "C" void kernel_launch(void* const* d_in, const int* in_sizes, int n_in,
                              void* d_out, int out_size, void* d_ws, size_t ws_size,
                              hipStream_t stream) {
    const float* q    = (const float*)d_in[0];
    const float* k    = (const float*)d_in[1];
    const float* v    = (const float*)d_in[2];
    // d_in[3] is the scalar BS (=64), baked into kernel constants.
    const int*   top2 = (const int*)d_in[4];
    float*       out  = (float*)d_out;

    if (ws_size < WS_NEEDED) {
        dim3 grid(NQ_TOT / 4), block(256);
        hipLaunchKernelGGL(blockattn_fallback, grid, block, 0, stream, q, k, v, top2, out);
        return;
    }

    float* parts = (float*)d_ws;

    hipLaunchKernelGGL(bucket_kernel,  dim3(NBUCKET * SSPLIT), dim3(256), 0, stream,
                       q, k, v, top2, parts);
    hipLaunchKernelGGL(combine_kernel, dim3(NQ_TOT * 16 / 256), dim3(256), 0, stream,
                       parts, out);
}